// Round 3
// baseline (67.663 us; speedup 1.0000x reference)
//
#include <hip/hip_runtime.h>

// Problem constants (from reference setup_inputs):
//   B=128 batch, L=4096 doc length, O=10 options, W=5 words/option
// out[b][o] = (sum_w sum_l prob[b][l] * (opt[b][o][w]==idx[b][l])) / #nonzero-words
#define BB 128
#define LL 4096
#define OO 10
#define WW 5

// One block per batch row: reads the doc row ONCE, evaluates all 10 options.
// 1024 threads -> each thread handles exactly 4 elements (1 int4 + 1 float4).
// Option words (50 ints) are block-uniform -> SGPR broadcast, zero VGPR cost.
__global__ __launch_bounds__(1024) void OptionAttentionSum_kernel(
    const int* __restrict__ doc_idx,     // (B, L) int32
    const float* __restrict__ doc_prob,  // (B, L) f32
    const int* __restrict__ options,     // (B, O, W) int32
    float* __restrict__ out)             // (B, O) f32
{
    const int b = blockIdx.x;
    const int t = threadIdx.x;

    // Block-uniform option words: 50 contiguous ints at options + b*50
    const int* opt = options + b * (OO * WW);
    int w[OO][WW];
#pragma unroll
    for (int o = 0; o < OO; ++o)
#pragma unroll
        for (int k = 0; k < WW; ++k)
            w[o][k] = opt[o * WW + k];

    const int4   d = ((const int4*)(doc_idx + (long)b * LL))[t];
    const float4 p = ((const float4*)(doc_prob + (long)b * LL))[t];

    float acc[OO];
#pragma unroll
    for (int o = 0; o < OO; ++o) acc[o] = 0.0f;

#pragma unroll
    for (int o = 0; o < OO; ++o) {
        acc[o] += p.x * (float)((d.x == w[o][0]) + (d.x == w[o][1]) + (d.x == w[o][2]) + (d.x == w[o][3]) + (d.x == w[o][4]));
        acc[o] += p.y * (float)((d.y == w[o][0]) + (d.y == w[o][1]) + (d.y == w[o][2]) + (d.y == w[o][3]) + (d.y == w[o][4]));
        acc[o] += p.z * (float)((d.z == w[o][0]) + (d.z == w[o][1]) + (d.z == w[o][2]) + (d.z == w[o][3]) + (d.z == w[o][4]));
        acc[o] += p.w * (float)((d.w == w[o][0]) + (d.w == w[o][1]) + (d.w == w[o][2]) + (d.w == w[o][3]) + (d.w == w[o][4]));
    }

    // Wave-64 shuffle reduction for each of the 10 accumulators
#pragma unroll
    for (int o = 0; o < OO; ++o)
#pragma unroll
        for (int off = 32; off > 0; off >>= 1)
            acc[o] += __shfl_down(acc[o], off, 64);

    __shared__ float wsum[16][OO];   // 16 waves x 10 options
    const int wave = t >> 6;
    const int lane = t & 63;
    if (lane == 0) {
#pragma unroll
        for (int o = 0; o < OO; ++o) wsum[wave][o] = acc[o];
    }
    __syncthreads();

    if (t < OO) {
        float total = 0.0f;
#pragma unroll
        for (int v = 0; v < 16; ++v) total += wsum[v][t];
        const int* ow = w[0] + t * WW;  // w is contiguous [OO][WW]
        const float divisor = (float)((ow[0] != 0) + (ow[1] != 0) + (ow[2] != 0) +
                                      (ow[3] != 0) + (ow[4] != 0));
        out[b * OO + t] = total / divisor;
    }
}

extern "C" void kernel_launch(void* const* d_in, const int* in_sizes, int n_in,
                              void* d_out, int out_size, void* d_ws, size_t ws_size,
                              hipStream_t stream) {
    const int*   doc_idx  = (const int*)d_in[0];
    const float* doc_prob = (const float*)d_in[1];
    const int*   options  = (const int*)d_in[2];
    float*       out      = (float*)d_out;

    OptionAttentionSum_kernel<<<BB, 1024, 0, stream>>>(doc_idx, doc_prob, options, out);
}

// Round 4
// 60.330 us; speedup vs baseline: 1.1215x; 1.1215x over previous
//
#include <hip/hip_runtime.h>

// Problem constants (from reference setup_inputs):
//   B=128 batch, L=4096 doc length, O=10 options, W=5 words/option
// out[b][o] = (sum_w sum_l prob[b][l] * (opt[b][o][w]==idx[b][l])) / #nonzero-words
#define BB 128
#define LL 4096
#define OO 10
#define WW 5

// Grid = B * (O/2) = 640 blocks, 256 threads. Each block evaluates TWO options
// for one batch row: halves VMEM instructions / L2 re-reads vs one-option-per-
// block (R2) while keeping 2.5 blocks/CU of parallelism (R3's 128-block fusion
// starved half the CUs). All option words are block-uniform with compile-time
// register indices -> SGPR-resident (R3's dynamic index forced VGPR spill).
__global__ __launch_bounds__(256) void OptionAttentionSum_kernel(
    const int* __restrict__ doc_idx,     // (B, L) int32
    const float* __restrict__ doc_prob,  // (B, L) f32
    const int* __restrict__ options,     // (B, O, W) int32
    float* __restrict__ out)             // (B, O) f32
{
    // XCD-locality swizzle: all 5 blocks of batch row b share blockIdx mod 8
    // -> same XCD L2 serves the doc row after first fetch.
    const int b    = blockIdx.x & (BB - 1);   // blockIdx % 128
    const int pair = blockIdx.x >> 7;         // 0..4
    const int o0 = pair * 2, o1 = pair * 2 + 1;
    const int t = threadIdx.x;

    const int* opt = options + (b * OO + o0) * WW;
    const int a0 = opt[0], a1 = opt[1], a2 = opt[2], a3 = opt[3], a4 = opt[4];
    const int b0 = opt[5], b1 = opt[6], b2 = opt[7], b3 = opt[8], b4 = opt[9];

    const int4*   idx4 = (const int4*)(doc_idx + (long)b * LL);
    const float4* p4   = (const float4*)(doc_prob + (long)b * LL);

    float accA = 0.0f, accB = 0.0f;
#pragma unroll
    for (int it = 0; it < 4; ++it) {
        const int i = it * 256 + t;
        const int4   d = idx4[i];
        const float4 p = p4[i];
        accA += p.x * (float)((d.x == a0) + (d.x == a1) + (d.x == a2) + (d.x == a3) + (d.x == a4));
        accA += p.y * (float)((d.y == a0) + (d.y == a1) + (d.y == a2) + (d.y == a3) + (d.y == a4));
        accA += p.z * (float)((d.z == a0) + (d.z == a1) + (d.z == a2) + (d.z == a3) + (d.z == a4));
        accA += p.w * (float)((d.w == a0) + (d.w == a1) + (d.w == a2) + (d.w == a3) + (d.w == a4));
        accB += p.x * (float)((d.x == b0) + (d.x == b1) + (d.x == b2) + (d.x == b3) + (d.x == b4));
        accB += p.y * (float)((d.y == b0) + (d.y == b1) + (d.y == b2) + (d.y == b3) + (d.y == b4));
        accB += p.z * (float)((d.z == b0) + (d.z == b1) + (d.z == b2) + (d.z == b3) + (d.z == b4));
        accB += p.w * (float)((d.w == b0) + (d.w == b1) + (d.w == b2) + (d.w == b3) + (d.w == b4));
    }

    // Wave-64 butterfly reduction for both accumulators
#pragma unroll
    for (int off = 32; off > 0; off >>= 1) {
        accA += __shfl_xor(accA, off, 64);
        accB += __shfl_xor(accB, off, 64);
    }

    __shared__ float wsumA[4], wsumB[4];
    const int wave = t >> 6;
    const int lane = t & 63;
    if (lane == 0) { wsumA[wave] = accA; wsumB[wave] = accB; }
    __syncthreads();

    if (t == 0) {
        const float totA = wsumA[0] + wsumA[1] + wsumA[2] + wsumA[3];
        const float totB = wsumB[0] + wsumB[1] + wsumB[2] + wsumB[3];
        const float divA = (float)((a0 != 0) + (a1 != 0) + (a2 != 0) + (a3 != 0) + (a4 != 0));
        const float divB = (float)((b0 != 0) + (b1 != 0) + (b2 != 0) + (b3 != 0) + (b4 != 0));
        out[b * OO + o0] = totA / divA;
        out[b * OO + o1] = totB / divB;
    }
}

extern "C" void kernel_launch(void* const* d_in, const int* in_sizes, int n_in,
                              void* d_out, int out_size, void* d_ws, size_t ws_size,
                              hipStream_t stream) {
    const int*   doc_idx  = (const int*)d_in[0];
    const float* doc_prob = (const float*)d_in[1];
    const int*   options  = (const int*)d_in[2];
    float*       out      = (float*)d_out;

    OptionAttentionSum_kernel<<<BB * (OO / 2), 256, 0, stream>>>(doc_idx, doc_prob, options, out);
}

// Round 5
// 59.150 us; speedup vs baseline: 1.1439x; 1.0199x over previous
//
#include <hip/hip_runtime.h>

// Problem constants (from reference setup_inputs):
//   B=128 batch, L=4096 doc length, O=10 options, W=5 words/option
// out[b][o] = (sum_w sum_l prob[b][l] * (opt[b][o][w]==idx[b][l])) / #nonzero-words
#define BB 128
#define LL 4096
#define OO 10
#define WW 5

// Best measured config (R2, 59.0 us): one option per block, 1280 blocks x 256.
// Kernel is latency-bound on cold HBM (harness's 268 MB poison fill evicts L2
// each iteration) -> max block count wins: 1280 blocks = 20 waves/CU of MLP.
// Fusing options per block (640 blocks: 60.3 us, 128 blocks: 67.7 us) regressed.
__global__ __launch_bounds__(256) void OptionAttentionSum_kernel(
    const int* __restrict__ doc_idx,     // (B, L) int32
    const float* __restrict__ doc_prob,  // (B, L) f32
    const int* __restrict__ options,     // (B, O, W) int32
    float* __restrict__ out)             // (B, O) f32
{
    // XCD-locality swizzle: all 10 blocks of batch row b share blockIdx mod 8
    // -> same XCD's L2 serves the doc row after the first fetch.
    const int b = blockIdx.x & (BB - 1);     // blockIdx % 128
    const int o = blockIdx.x >> 7;           // / 128
    const int bo = b * OO + o;
    const int t = threadIdx.x;

    // Block-uniform option words -> scalar loads / SGPR broadcast
    const int* opt = options + bo * WW;
    const int w0 = opt[0], w1 = opt[1], w2 = opt[2], w3 = opt[3], w4 = opt[4];

    const int4*   idx4 = (const int4*)(doc_idx + (long)b * LL);
    const float4* p4   = (const float4*)(doc_prob + (long)b * LL);

    float acc = 0.0f;
    // L/4 = 1024 vec4 elements; 256 threads -> 4 iterations, coalesced 16B/lane
#pragma unroll
    for (int it = 0; it < 4; ++it) {
        const int i = it * 256 + t;
        const int4   d = idx4[i];
        const float4 p = p4[i];
        acc += p.x * (float)((d.x == w0) + (d.x == w1) + (d.x == w2) + (d.x == w3) + (d.x == w4));
        acc += p.y * (float)((d.y == w0) + (d.y == w1) + (d.y == w2) + (d.y == w3) + (d.y == w4));
        acc += p.z * (float)((d.z == w0) + (d.z == w1) + (d.z == w2) + (d.z == w3) + (d.z == w4));
        acc += p.w * (float)((d.w == w0) + (d.w == w1) + (d.w == w2) + (d.w == w3) + (d.w == w4));
    }

    // Wave-64 butterfly reduction
#pragma unroll
    for (int off = 32; off > 0; off >>= 1)
        acc += __shfl_xor(acc, off, 64);

    __shared__ float warp_sums[4];
    const int wave = t >> 6;
    const int lane = t & 63;
    if (lane == 0) warp_sums[wave] = acc;
    __syncthreads();

    if (t == 0) {
        const float total = warp_sums[0] + warp_sums[1] + warp_sums[2] + warp_sums[3];
        const float divisor = (float)((w0 != 0) + (w1 != 0) + (w2 != 0) + (w3 != 0) + (w4 != 0));
        out[bo] = total / divisor;
    }
}

extern "C" void kernel_launch(void* const* d_in, const int* in_sizes, int n_in,
                              void* d_out, int out_size, void* d_ws, size_t ws_size,
                              hipStream_t stream) {
    const int*   doc_idx  = (const int*)d_in[0];
    const float* doc_prob = (const float*)d_in[1];
    const int*   options  = (const int*)d_in[2];
    float*       out      = (float*)d_out;

    OptionAttentionSum_kernel<<<BB * OO, 256, 0, stream>>>(doc_idx, doc_prob, options, out);
}